// Round 1
// baseline (19485.991 us; speedup 1.0000x reference)
//
#include <hip/hip_runtime.h>

typedef _Float16 v8h __attribute__((ext_vector_type(8)));
typedef float v4f __attribute__((ext_vector_type(4)));

// ---- workspace layout (bytes) ----
#define OFF_BAR   0
#define OFF_X1    1024
#define OFF_X2    (OFF_X1 + 2*1024*1024)
#define OFF_W1    (OFF_X2 + 2*1024*1024)
#define OFF_W2    (OFF_W1 + 2*1024*1024)
#define OFF_B1    (OFF_W2 + 4*1024*1024)
#define OFF_B2    (OFF_B1 + 8192)
#define WS_NEED   (OFF_B2 + 8192)

// Pack weights into MFMA-fragment order:
// W1p[nt][k32][lane][el] for Whh1 (K=512, 16 k32-chunks)
// W2p[nt][k32][lane][el] for [Wih2 | Whh2] (K=1024, 32 chunks)
// frag layout (16x16x32): n = nt*16 + (lane&15), k = k32*32 + (lane>>4)*8 + el
__global__ __launch_bounds__(256, 1)
void lstm_prep(const float* __restrict__ Whh1, const float* __restrict__ Wih2,
               const float* __restrict__ Whh2, const float* __restrict__ bih1,
               const float* __restrict__ bhh1, const float* __restrict__ bih2,
               const float* __restrict__ bhh2,
               _Float16* __restrict__ W1p, _Float16* __restrict__ W2p,
               float* __restrict__ bs1, float* __restrict__ bs2)
{
  const int total = 1048576 + 2097152 + 4096;
  for (int i = blockIdx.x*blockDim.x + threadIdx.x; i < total; i += gridDim.x*blockDim.x) {
    if (i < 1048576) {
      int nt = i >> 13, rem = i & 8191;
      int k32 = rem >> 9, c = rem & 511;
      int lane = c >> 3, el = c & 7;
      int n = nt*16 + (lane & 15);
      int k = k32*32 + (lane >> 4)*8 + el;
      W1p[i] = (_Float16)Whh1[n*512 + k];
    } else if (i < 3145728) {
      int j = i - 1048576;
      int nt = j >> 14, rem = j & 16383;
      int k32 = rem >> 9, c = rem & 511;
      int lane = c >> 3, el = c & 7;
      int n = nt*16 + (lane & 15);
      int k = k32*32 + (lane >> 4)*8 + el;
      float v = (k < 512) ? Wih2[n*512 + k] : Whh2[n*512 + (k - 512)];
      W2p[j] = (_Float16)v;
    } else {
      int n = i - 3145728;
      if (n < 2048) bs1[n] = bih1[n] + bhh1[n];
      else          bs2[n-2048] = bih2[n-2048] + bhh2[n-2048];
    }
  }
}

__device__ __forceinline__ float sigmoidf_(float z) { return 1.f / (1.f + __expf(-z)); }
__device__ __forceinline__ float tanhf_(float z)    { return 1.f - 2.f/(1.f + __expf(2.f*z)); }

// 256 blocks x 256 threads, persistent. Block tile: 64 batch x 32 hidden (=128 gate cols).
// Each wave does all 32 MFMA tiles over its K-quarter; 4-way LDS reduce; fp32 epilogue.
__global__ __launch_bounds__(256, 1)
void lstm_main(const float* __restrict__ x, const float* __restrict__ Wih1,
               const float* __restrict__ Wl, const float* __restrict__ blv,
               _Float16* __restrict__ X1, _Float16* __restrict__ X2,
               const _Float16* __restrict__ W1, const _Float16* __restrict__ W2,
               const float* __restrict__ bs1, const float* __restrict__ bs2,
               int* __restrict__ bar, float* __restrict__ out)
{
  __shared__ float gred[64*132];   // [b_loc][gate*32+jj], pad 132 to break conflicts
  const int tid  = threadIdx.x;
  const int wave = tid >> 6, lane = tid & 63;
  const int quad = lane >> 4, lc = lane & 15;
  const int bid  = blockIdx.x;
  const int jgrp = bid >> 3;
  const int ht   = (bid & 7)*2 + (jgrp >> 4);  // XCD swizzle: same-ht blocks share an XCD
  const int bt   = jgrp & 15;

  float c1[8], c2[8];
  #pragma unroll
  for (int i = 0; i < 8; i++) { c1[i] = 0.f; c2[i] = 0.f; }

  for (int r = 0; r < 320; r++) {
    const bool odd    = (r & 1) != 0;
    const bool phase1 = r < 256;
    const _Float16* Ap; const _Float16* Wp; const float* bs;
    int nk32, wk32;
    if (!odd) {
      if (phase1) { Ap = X1; Wp = W1; bs = bs1; nk32 = 16; wk32 = 16; } // cell1: h1 @ Whh1
      else        { Ap = X2; Wp = W2; bs = bs2; nk32 = 32; wk32 = 32; } // fut-a: [tmp|h1] @ [Wih2|Whh2]
    } else        { Ap = X1; Wp = W2; bs = bs2; nk32 = 32; wk32 = 32; } // cell2/fut-b: [h1|h2] @ [Wih2|Whh2]

    v4f acc[4][8];
    #pragma unroll
    for (int mt = 0; mt < 4; mt++)
      #pragma unroll
      for (int t = 0; t < 8; t++) acc[mt][t] = (v4f){0.f,0.f,0.f,0.f};

    const int itN = nk32 >> 2;
    const int it0 = wave * itN;
    const _Float16* pa[4];
    #pragma unroll
    for (int mt = 0; mt < 4; mt++)
      pa[mt] = Ap + (size_t)((bt*4+mt)*32)*512 + lane*8;
    const _Float16* pb[8];
    #pragma unroll
    for (int t = 0; t < 8; t++) {
      int ntg = (t>>1)*32 + ht*2 + (t&1);   // global 16-col ntile for (gate=t>>1, half=t&1)
      pb[t] = Wp + (size_t)ntg * wk32 * 512 + lane*8;
    }

    #pragma unroll 2
    for (int kk = it0; kk < it0 + itN; kk++) {
      v8h a[4], b[8];
      #pragma unroll
      for (int mt = 0; mt < 4; mt++)
        a[mt] = *(const v8h*)(pa[mt] + (size_t)kk*512);
      #pragma unroll
      for (int t = 0; t < 8; t++)
        b[t] = *(const v8h*)(pb[t] + (size_t)kk*512);
      #pragma unroll
      for (int mt = 0; mt < 4; mt++)
        #pragma unroll
        for (int t = 0; t < 8; t++)
          acc[mt][t] = __builtin_amdgcn_mfma_f32_16x16x32_f16(a[mt], b[t], acc[mt][t], 0, 0, 0);
    }

    // ---- cross-wave K reduction in LDS ----
    if (wave == 0) {
      #pragma unroll
      for (int mt = 0; mt < 4; mt++)
        #pragma unroll
        for (int t = 0; t < 8; t++) {
          int base = (mt*16 + quad*4)*132 + t*16 + lc;
          #pragma unroll
          for (int rr = 0; rr < 4; rr++) gred[base + rr*132] = acc[mt][t][rr];
        }
    }
    __syncthreads();
    if (wave != 0) {
      #pragma unroll
      for (int mt = 0; mt < 4; mt++)
        #pragma unroll
        for (int t = 0; t < 8; t++) {
          int base = (mt*16 + quad*4)*132 + t*16 + lc;
          #pragma unroll
          for (int rr = 0; rr < 4; rr++) atomicAdd(&gred[base + rr*132], acc[mt][t][rr]);
        }
    }
    __syncthreads();

    // ---- fp32 LSTM epilogue: 8 elements/thread ----
    const int tstep = r >> 1;
    const int fs    = (r - 256) >> 1;
    #pragma unroll
    for (int i = 0; i < 8; i++) {
      int e = tid + 256*i;
      int b_loc = e >> 5, jj = e & 31;
      float g0 = gred[b_loc*132 + jj];
      float g1 = gred[b_loc*132 + 32 + jj];
      float g2 = gred[b_loc*132 + 64 + jj];
      float g3 = gred[b_loc*132 + 96 + jj];
      int hh = ht*32 + jj;                       // hidden index 0..511
      g0 += bs[hh]; g1 += bs[512+hh]; g2 += bs[1024+hh]; g3 += bs[1536+hh];
      int b = bt*64 + b_loc;
      if (!odd && phase1) {                      // x @ Wih1^T (K=4, exact fp32)
        const float* xr = x + ((size_t)tstep*1024 + b)*4;
        float x0 = xr[0], x1 = xr[1], x2 = xr[2], x3 = xr[3];
        const float* w0 = Wih1 + (size_t)hh*4;
        const float* w1 = Wih1 + (size_t)(512+hh)*4;
        const float* w2 = Wih1 + (size_t)(1024+hh)*4;
        const float* w3 = Wih1 + (size_t)(1536+hh)*4;
        g0 += x0*w0[0] + x1*w0[1] + x2*w0[2] + x3*w0[3];
        g1 += x0*w1[0] + x1*w1[1] + x2*w1[2] + x3*w1[3];
        g2 += x0*w2[0] + x1*w2[1] + x2*w2[2] + x3*w2[3];
        g3 += x0*w3[0] + x1*w3[1] + x2*w3[2] + x3*w3[3];
      }
      float ig = sigmoidf_(g0), fg = sigmoidf_(g1);
      float gg = tanhf_(g2),   og = sigmoidf_(g3);
      float c = odd ? c2[i] : c1[i];
      c = fg*c + ig*gg;
      if (odd) c2[i] = c; else c1[i] = c;
      float hf = og * tanhf_(c);

      // store h in A-fragment pack order
      int mtile = b >> 4, m = b & 15;
      int lane_p = ((jj >> 3) << 4) + m;
      int el = jj & 7;
      size_t basep = (size_t)lane_p*8 + el;
      _Float16 hv = (_Float16)hf;
      if (!odd) {                                // h1 -> X1[k32=ht], X2[k32=16+ht]
        X1[((size_t)(mtile*32 + ht))*512 + basep] = hv;
        X2[((size_t)(mtile*32 + 16 + ht))*512 + basep] = hv;
      } else {                                   // h2 -> X1[k32=16+ht] (+X2 tmp in phase1)
        X1[((size_t)(mtile*32 + 16 + ht))*512 + basep] = hv;
        if (phase1) X2[((size_t)(mtile*32 + ht))*512 + basep] = hv;
        else        gred[b_loc*132 + jj] = hf;   // stash fp32 h2 for out-projection
      }
    }

    if (odd && !phase1) {                        // out = h2 @ Wl^T + bl (partial over 32 cols)
      __syncthreads();
      int bb = tid >> 2, o = tid & 3;
      float s = (ht == 0) ? blv[o] : 0.f;
      const float* wl = Wl + (size_t)o*512 + ht*32;
      #pragma unroll
      for (int jj = 0; jj < 32; jj++) s += gred[bb*132 + jj] * wl[jj];
      atomicAdd(&out[(((size_t)fs*1024) + bt*64 + bb)*4 + o], s);
    }

    // ---- grid barrier (device-scope, sense via monotonic counter) ----
    __syncthreads();
    if (tid == 0) {
      __hip_atomic_fetch_add(bar, 1, __ATOMIC_ACQ_REL, __HIP_MEMORY_SCOPE_AGENT);
      const int target = 256*(r+1);
      while (__hip_atomic_load(bar, __ATOMIC_ACQUIRE, __HIP_MEMORY_SCOPE_AGENT) < target) {
        __builtin_amdgcn_s_sleep(2);
      }
    }
    __syncthreads();
  }
}

extern "C" void kernel_launch(void* const* d_in, const int* in_sizes, int n_in,
                              void* d_out, int out_size, void* d_ws, size_t ws_size,
                              hipStream_t stream) {
  const float* x    = (const float*)d_in[0];
  const float* Wih1 = (const float*)d_in[1];
  const float* Whh1 = (const float*)d_in[2];
  const float* bih1 = (const float*)d_in[3];
  const float* bhh1 = (const float*)d_in[4];
  const float* Wih2 = (const float*)d_in[5];
  const float* Whh2 = (const float*)d_in[6];
  const float* bih2 = (const float*)d_in[7];
  const float* bhh2 = (const float*)d_in[8];
  const float* Wl   = (const float*)d_in[9];
  const float* bl   = (const float*)d_in[10];

  char* ws = (char*)d_ws;
  int*      bar = (int*)(ws + OFF_BAR);
  _Float16* X1  = (_Float16*)(ws + OFF_X1);
  _Float16* X2  = (_Float16*)(ws + OFF_X2);
  _Float16* W1p = (_Float16*)(ws + OFF_W1);
  _Float16* W2p = (_Float16*)(ws + OFF_W2);
  float*    bs1 = (float*)(ws + OFF_B1);
  float*    bs2 = (float*)(ws + OFF_B2);

  // zero barrier + X1 + X2 (h state starts at 0); zero out (atomic accumulation)
  hipMemsetAsync(ws, 0, (size_t)OFF_W1, stream);
  hipMemsetAsync(d_out, 0, (size_t)out_size * sizeof(float), stream);

  lstm_prep<<<2048, 256, 0, stream>>>(Whh1, Wih2, Whh2, bih1, bhh1, bih2, bhh2,
                                      W1p, W2p, bs1, bs2);
  lstm_main<<<256, 256, 0, stream>>>(x, Wih1, Wl, bl, X1, X2, W1p, W2p, bs1, bs2,
                                     bar, (float*)d_out);
}

// Round 2
// 14274.933 us; speedup vs baseline: 1.3650x; 1.3650x over previous
//
#include <hip/hip_runtime.h>

typedef _Float16 v8h __attribute__((ext_vector_type(8)));
typedef float v4f __attribute__((ext_vector_type(4)));

// ---- workspace layout (bytes) ----
#define OFF_BAR   0
#define OFF_AO0   4096
#define OFF_AO1   (OFF_AO0 + (1<<21))
#define OFF_AF0   (OFF_AO1 + (1<<21))
#define OFF_AF1   (OFF_AF0 + (1<<21))
#define OFF_W1    (OFF_AF1 + (1<<21))
#define OFF_W2    (OFF_W1 + (1<<21))
#define OFF_B1    (OFF_W2 + (1<<22))
#define OFF_B2    (OFF_B1 + 8192)

// Pack weights into MFMA B-fragment order:
// frag layout (16x16x32): n = nt*16 + (lane&15), k = k32*32 + (lane>>4)*8 + el
__global__ __launch_bounds__(256, 1)
void lstm_prep(const float* __restrict__ Whh1, const float* __restrict__ Wih2,
               const float* __restrict__ Whh2, const float* __restrict__ bih1,
               const float* __restrict__ bhh1, const float* __restrict__ bih2,
               const float* __restrict__ bhh2,
               _Float16* __restrict__ W1p, _Float16* __restrict__ W2p,
               float* __restrict__ bs1, float* __restrict__ bs2)
{
  const int total = 1048576 + 2097152 + 4096;
  for (int i = blockIdx.x*blockDim.x + threadIdx.x; i < total; i += gridDim.x*blockDim.x) {
    if (i < 1048576) {
      int nt = i >> 13, rem = i & 8191;
      int k32 = rem >> 9, c = rem & 511;
      int lane = c >> 3, el = c & 7;
      int n = nt*16 + (lane & 15);
      int k = k32*32 + (lane >> 4)*8 + el;
      W1p[i] = (_Float16)Whh1[n*512 + k];
    } else if (i < 3145728) {
      int j = i - 1048576;
      int nt = j >> 14, rem = j & 16383;
      int k32 = rem >> 9, c = rem & 511;
      int lane = c >> 3, el = c & 7;
      int n = nt*16 + (lane & 15);
      int k = k32*32 + (lane >> 4)*8 + el;
      float v = (k < 512) ? Wih2[n*512 + k] : Whh2[n*512 + (k - 512)];
      W2p[j] = (_Float16)v;
    } else {
      int n = i - 3145728;
      if (n < 2048) bs1[n] = bih1[n] + bhh1[n];
      else          bs2[n-2048] = bih2[n-2048] + bhh2[n-2048];
    }
  }
}

__device__ __forceinline__ float sigmoidf_(float z) { return 1.f / (1.f + __expf(-z)); }
__device__ __forceinline__ float tanhf_(float z)    { return 1.f - 2.f/(1.f + __expf(2.f*z)); }

__device__ __forceinline__ v8h ld_frag_sys(const _Float16* p) {
  union { unsigned long long u[2]; v8h h; } cv;
  const unsigned long long* q = (const unsigned long long*)p;
  cv.u[0] = __hip_atomic_load(q,     __ATOMIC_RELAXED, __HIP_MEMORY_SCOPE_SYSTEM);
  cv.u[1] = __hip_atomic_load(q + 1, __ATOMIC_RELAXED, __HIP_MEMORY_SCOPE_SYSTEM);
  return cv.h;
}

// 256 blocks x 256 threads, persistent. Block tile: 64 batch x 32 hidden (=128 gate cols).
// h-state exchange via L2-bypassing (sc0 sc1) relaxed atomics; weights stay L2-hot.
// Double-buffered state by time parity eliminates same-round read/write races.
__global__ __launch_bounds__(256, 1)
void lstm_main(const float* __restrict__ x, const float* __restrict__ Wih1,
               const float* __restrict__ Wl, const float* __restrict__ blv,
               _Float16* __restrict__ AO0, _Float16* __restrict__ AO1,
               _Float16* __restrict__ AF0, _Float16* __restrict__ AF1,
               const _Float16* __restrict__ W1, const _Float16* __restrict__ W2,
               const float* __restrict__ bs1, const float* __restrict__ bs2,
               int* __restrict__ bar, float* __restrict__ out)
{
  __shared__ float gred[64*132];   // [b_loc][gate*32+jj], pad 132
  __shared__ float stash[64*33];   // fp32 h2 for out-projection
  const int tid  = threadIdx.x;
  const int wave = tid >> 6, lane = tid & 63;
  const int quad = lane >> 4, lc = lane & 15;
  const int bid  = blockIdx.x;
  const int jgrp = bid >> 3;
  const int ht   = (bid & 7)*2 + (jgrp >> 4);  // XCD swizzle: same-ht blocks share an XCD
  const int bt   = jgrp & 15;

  _Float16* const AOv[2] = {AO0, AO1};
  _Float16* const AFv[2] = {AF0, AF1};

  // epilogue ownership: b_loc = tid>>2 (batch row in tile), oct = tid&3 (8-wide jj octet)
  const int b_loc = tid >> 2, oct = tid & 3;
  const int m = b_loc & 15, mtile_e = bt*4 + (b_loc >> 4);
  const int lane_p = oct*16 + m;

  float c1[8], c2[8];
  #pragma unroll
  for (int i = 0; i < 8; i++) { c1[i] = 0.f; c2[i] = 0.f; }

  for (int r = 0; r < 320; r++) {
    const bool odd    = (r & 1) != 0;
    const bool p1     = r < 256;
    const int  t      = r >> 1;
    const int  s      = (r - 256) >> 1;
    const _Float16* Ap; const _Float16* Wp; const float* bs;
    int nk32, wk32;
    if (p1) {
      if (!odd) { Ap = AOv[(t+1)&1]; Wp = W1; bs = bs1; nk32 = 16; wk32 = 16; }
      else      { Ap = AOv[t&1];     Wp = W2; bs = bs2; nk32 = 32; wk32 = 32; }
    } else {
      if (!odd) { Ap = AFv[(s+1)&1]; Wp = W2; bs = bs2; nk32 = 32; wk32 = 32; }
      else      { Ap = AOv[s&1];     Wp = W2; bs = bs2; nk32 = 32; wk32 = 32; }
    }

    v4f acc[4][8];
    #pragma unroll
    for (int mt = 0; mt < 4; mt++)
      #pragma unroll
      for (int tt = 0; tt < 8; tt++) acc[mt][tt] = (v4f){0.f,0.f,0.f,0.f};

    const int itN = nk32 >> 2;
    const int it0 = wave * itN;
    const _Float16* pa[4];
    #pragma unroll
    for (int mt = 0; mt < 4; mt++)
      pa[mt] = Ap + (size_t)((bt*4+mt)*32)*512 + lane*8;
    const _Float16* pb[8];
    #pragma unroll
    for (int tt = 0; tt < 8; tt++) {
      int ntg = (tt>>1)*32 + ht*2 + (tt&1);
      pb[tt] = Wp + (size_t)ntg * wk32 * 512 + lane*8;
    }

    #pragma unroll 2
    for (int kk = it0; kk < it0 + itN; kk++) {
      v8h a[4], b[8];
      #pragma unroll
      for (int mt = 0; mt < 4; mt++)
        a[mt] = ld_frag_sys(pa[mt] + (size_t)kk*512);
      #pragma unroll
      for (int tt = 0; tt < 8; tt++)
        b[tt] = *(const v8h*)(pb[tt] + (size_t)kk*512);
      #pragma unroll
      for (int mt = 0; mt < 4; mt++)
        #pragma unroll
        for (int tt = 0; tt < 8; tt++)
          acc[mt][tt] = __builtin_amdgcn_mfma_f32_16x16x32_f16(a[mt], b[tt], acc[mt][tt], 0, 0, 0);
    }

    // ---- cross-wave K reduction in LDS ----
    if (wave == 0) {
      #pragma unroll
      for (int mt = 0; mt < 4; mt++)
        #pragma unroll
        for (int tt = 0; tt < 8; tt++) {
          int base = (mt*16 + quad*4)*132 + tt*16 + lc;
          #pragma unroll
          for (int rr = 0; rr < 4; rr++) gred[base + rr*132] = acc[mt][tt][rr];
        }
    }
    __syncthreads();
    if (wave != 0) {
      #pragma unroll
      for (int mt = 0; mt < 4; mt++)
        #pragma unroll
        for (int tt = 0; tt < 8; tt++) {
          int base = (mt*16 + quad*4)*132 + tt*16 + lc;
          #pragma unroll
          for (int rr = 0; rr < 4; rr++) atomicAdd(&gred[base + rr*132], acc[mt][tt][rr]);
        }
    }
    __syncthreads();

    // ---- fp32 LSTM epilogue: thread owns (b_loc, jj = oct*8 .. oct*8+7) ----
    float g[4][8];
    #pragma unroll
    for (int g4 = 0; g4 < 4; g4++) {
      v4f v0 = *(const v4f*)&gred[b_loc*132 + g4*32 + oct*8];
      v4f v1 = *(const v4f*)&gred[b_loc*132 + g4*32 + oct*8 + 4];
      const v4f bv0 = *(const v4f*)&bs[g4*512 + ht*32 + oct*8];
      const v4f bv1 = *(const v4f*)&bs[g4*512 + ht*32 + oct*8 + 4];
      #pragma unroll
      for (int j = 0; j < 4; j++) { g[g4][j] = v0[j] + bv0[j]; g[g4][4+j] = v1[j] + bv1[j]; }
    }
    const int b = bt*64 + b_loc;
    if (!odd && p1) {                      // + x @ Wih1^T (K=4, exact fp32)
      const v4f xv = *(const v4f*)(x + ((size_t)t*1024 + b)*4);
      #pragma unroll
      for (int g4 = 0; g4 < 4; g4++)
        #pragma unroll
        for (int j = 0; j < 8; j++) {
          int hh = ht*32 + oct*8 + j;
          const v4f w = *(const v4f*)(Wih1 + (size_t)(g4*512 + hh)*4);
          g[g4][j] += xv[0]*w[0] + xv[1]*w[1] + xv[2]*w[2] + xv[3]*w[3];
        }
    }

    union { _Float16 h8[8]; unsigned long long u[2]; } hv;
    #pragma unroll
    for (int j = 0; j < 8; j++) {
      float ig = sigmoidf_(g[0][j]), fg = sigmoidf_(g[1][j]);
      float gg = tanhf_(g[2][j]),    og = sigmoidf_(g[3][j]);
      float c = odd ? c2[j] : c1[j];
      c = fg*c + ig*gg;
      if (odd) c2[j] = c; else c1[j] = c;
      float hf = og * tanhf_(c);
      hv.h8[j] = (_Float16)hf;
      if (odd && !p1) stash[b_loc*33 + oct*8 + j] = hf;
    }

    // ---- h stores: two 8B system-scope relaxed atomics per 16B destination ----
    auto st16 = [&](_Float16* basep, int chunk) {
      unsigned long long* p = (unsigned long long*)(basep + (size_t)chunk*512 + lane_p*8);
      __hip_atomic_store(p,     hv.u[0], __ATOMIC_RELAXED, __HIP_MEMORY_SCOPE_SYSTEM);
      __hip_atomic_store(p + 1, hv.u[1], __ATOMIC_RELAXED, __HIP_MEMORY_SCOPE_SYSTEM);
    };
    const int cb = mtile_e*32;
    if (p1) {
      if (!odd) {                       // h1(t) -> AO[t&1].ht ; AF[t&1].16+ht
        st16(AOv[t&1], cb + ht);
        st16(AFv[t&1], cb + 16 + ht);
      } else {                          // h2(t) -> AO[(t+1)&1].16+ht ; tmp -> AF[0/1].ht
        st16(AOv[(t+1)&1], cb + 16 + ht);
        st16(AFv[0], cb + ht);
        st16(AFv[1], cb + ht);
      }
    } else {
      if (!odd) {                       // h1f(s) -> AF[s&1].16+ht ; AO[s&1].ht
        st16(AFv[s&1], cb + 16 + ht);
        st16(AOv[s&1], cb + ht);
      } else {                          // h2f(s) -> AO[(s+1)&1].16+ht
        st16(AOv[(s+1)&1], cb + 16 + ht);
      }
    }

    if (odd && !p1) {                   // out = h2f @ Wl^T + bl (partial over this ht's 32 cols)
      __syncthreads();
      int bb = tid >> 2, o = tid & 3;
      float sacc = (ht == 0) ? blv[o] : 0.f;
      const float* wl = Wl + (size_t)o*512 + ht*32;
      #pragma unroll
      for (int jj = 0; jj < 32; jj++) sacc += stash[bb*33 + jj] * wl[jj];
      atomicAdd(&out[(((size_t)s*1024) + bt*64 + bb)*4 + o], sacc);
    }

    // ---- per-bt-group barrier: relaxed add + relaxed poll (no cache maintenance) ----
    __syncthreads();
    if (tid == 0) {
      int* ctr = bar + bt*32;           // 128B-spaced counters
      __hip_atomic_fetch_add(ctr, 1, __ATOMIC_RELAXED, __HIP_MEMORY_SCOPE_AGENT);
      const int target = 16*(r+1);
      while (__hip_atomic_load(ctr, __ATOMIC_RELAXED, __HIP_MEMORY_SCOPE_AGENT) < target)
        __builtin_amdgcn_s_sleep(1);
    }
    __syncthreads();
  }
}

extern "C" void kernel_launch(void* const* d_in, const int* in_sizes, int n_in,
                              void* d_out, int out_size, void* d_ws, size_t ws_size,
                              hipStream_t stream) {
  const float* x    = (const float*)d_in[0];
  const float* Wih1 = (const float*)d_in[1];
  const float* Whh1 = (const float*)d_in[2];
  const float* bih1 = (const float*)d_in[3];
  const float* bhh1 = (const float*)d_in[4];
  const float* Wih2 = (const float*)d_in[5];
  const float* Whh2 = (const float*)d_in[6];
  const float* bih2 = (const float*)d_in[7];
  const float* bhh2 = (const float*)d_in[8];
  const float* Wl   = (const float*)d_in[9];
  const float* bl   = (const float*)d_in[10];

  char* ws = (char*)d_ws;
  int*      bar = (int*)(ws + OFF_BAR);
  _Float16* AO0 = (_Float16*)(ws + OFF_AO0);
  _Float16* AO1 = (_Float16*)(ws + OFF_AO1);
  _Float16* AF0 = (_Float16*)(ws + OFF_AF0);
  _Float16* AF1 = (_Float16*)(ws + OFF_AF1);
  _Float16* W1p = (_Float16*)(ws + OFF_W1);
  _Float16* W2p = (_Float16*)(ws + OFF_W2);
  float*    bs1 = (float*)(ws + OFF_B1);
  float*    bs2 = (float*)(ws + OFF_B2);

  // zero barrier + state buffers (h,c start at 0); zero out (atomic accumulation)
  hipMemsetAsync(ws, 0, (size_t)OFF_W1, stream);
  hipMemsetAsync(d_out, 0, (size_t)out_size * sizeof(float), stream);

  lstm_prep<<<2048, 256, 0, stream>>>(Whh1, Wih2, Whh2, bih1, bhh1, bih2, bhh2,
                                      W1p, W2p, bs1, bs2);
  lstm_main<<<256, 256, 0, stream>>>(x, Wih1, Wl, bl, AO0, AO1, AF0, AF1,
                                     W1p, W2p, bs1, bs2, bar, (float*)d_out);
}

// Round 3
// 4710.725 us; speedup vs baseline: 4.1365x; 3.0303x over previous
//
#include <hip/hip_runtime.h>

typedef _Float16 v8h __attribute__((ext_vector_type(8)));
typedef float v4f __attribute__((ext_vector_type(4)));

// ---- workspace layout (bytes) ----
#define OFF_BAR   0
#define OFF_AO0   4096
#define OFF_AO1   (OFF_AO0 + (1<<21))
#define OFF_AF0   (OFF_AO1 + (1<<21))
#define OFF_AF1   (OFF_AF0 + (1<<21))
#define OFF_W1    (OFF_AF1 + (1<<21))
#define OFF_W2    (OFF_W1 + (1<<21))
#define OFF_B1    (OFF_W2 + (1<<22))
#define OFF_B2    (OFF_B1 + 8192)

// Pack weights into MFMA B-fragment order:
// frag layout (16x16x32): n = nt*16 + (lane&15), k = k32*32 + (lane>>4)*8 + el
__global__ __launch_bounds__(256, 1)
void lstm_prep(const float* __restrict__ Whh1, const float* __restrict__ Wih2,
               const float* __restrict__ Whh2, const float* __restrict__ bih1,
               const float* __restrict__ bhh1, const float* __restrict__ bih2,
               const float* __restrict__ bhh2,
               _Float16* __restrict__ W1p, _Float16* __restrict__ W2p,
               float* __restrict__ bs1, float* __restrict__ bs2)
{
  const int total = 1048576 + 2097152 + 4096;
  for (int i = blockIdx.x*blockDim.x + threadIdx.x; i < total; i += gridDim.x*blockDim.x) {
    if (i < 1048576) {
      int nt = i >> 13, rem = i & 8191;
      int k32 = rem >> 9, c = rem & 511;
      int lane = c >> 3, el = c & 7;
      int n = nt*16 + (lane & 15);
      int k = k32*32 + (lane >> 4)*8 + el;
      W1p[i] = (_Float16)Whh1[n*512 + k];
    } else if (i < 3145728) {
      int j = i - 1048576;
      int nt = j >> 14, rem = j & 16383;
      int k32 = rem >> 9, c = rem & 511;
      int lane = c >> 3, el = c & 7;
      int n = nt*16 + (lane & 15);
      int k = k32*32 + (lane >> 4)*8 + el;
      float v = (k < 512) ? Wih2[n*512 + k] : Whh2[n*512 + (k - 512)];
      W2p[j] = (_Float16)v;
    } else {
      int n = i - 3145728;
      if (n < 2048) bs1[n] = bih1[n] + bhh1[n];
      else          bs2[n-2048] = bih2[n-2048] + bhh2[n-2048];
    }
  }
}

__device__ __forceinline__ float sigmoidf_(float z) { return 1.f / (1.f + __expf(-z)); }
__device__ __forceinline__ float tanhf_(float z)    { return 1.f - 2.f/(1.f + __expf(2.f*z)); }

// agent-scope relaxed 16B fragment load (2x8B): bypasses L1/L2, cached in MALL
__device__ __forceinline__ v8h ld_frag_dev(const _Float16* p) {
  union { unsigned long long u[2]; v8h h; } cv;
  const unsigned long long* q = (const unsigned long long*)p;
  cv.u[0] = __hip_atomic_load(q,     __ATOMIC_RELAXED, __HIP_MEMORY_SCOPE_AGENT);
  cv.u[1] = __hip_atomic_load(q + 1, __ATOMIC_RELAXED, __HIP_MEMORY_SCOPE_AGENT);
  return cv.h;
}

// 256 blocks x 256 threads, persistent. Block tile: 64 batch x 32 hidden (=128 gate cols).
// h-state exchange via AGENT-relaxed atomics (MALL-resident, write-back — no HBM RTT).
// Non-atomic two-stage pairwise K-reduce in LDS. Double-buffered state by time parity.
__global__ __launch_bounds__(256, 1)
void lstm_main(const float* __restrict__ x, const float* __restrict__ Wih1,
               const float* __restrict__ Wl, const float* __restrict__ blv,
               _Float16* __restrict__ AO0, _Float16* __restrict__ AO1,
               _Float16* __restrict__ AF0, _Float16* __restrict__ AF1,
               const _Float16* __restrict__ W1, const _Float16* __restrict__ W2,
               const float* __restrict__ bs1, const float* __restrict__ bs2,
               int* __restrict__ bar, float* __restrict__ out)
{
  __shared__ float lred[16384];    // 64KB: two 32KB regions (acc dump / gred halves)
  const int tid  = threadIdx.x;
  const int wave = tid >> 6, lane = tid & 63;
  const int quad = lane >> 4, lc = lane & 15;
  const int bid  = blockIdx.x;
  const int jgrp = bid >> 3;
  const int ht   = (bid & 7)*2 + (jgrp >> 4);  // XCD swizzle: same-ht blocks share an XCD
  const int bt   = jgrp & 15;

  _Float16* const AOv[2] = {AO0, AO1};
  _Float16* const AFv[2] = {AF0, AF1};

  // epilogue ownership: b_loc = tid>>2 (batch row in tile), oct = tid&3 (8-wide jj octet)
  const int b_loc = tid >> 2, oct = tid & 3;
  const int m = b_loc & 15, mtile_e = bt*4 + (b_loc >> 4);
  const int lane_p = oct*16 + m;

  float c1[8], c2[8];
  #pragma unroll
  for (int i = 0; i < 8; i++) { c1[i] = 0.f; c2[i] = 0.f; }

  for (int r = 0; r < 320; r++) {
    const bool odd    = (r & 1) != 0;
    const bool p1     = r < 256;
    const int  t      = r >> 1;
    const int  s      = (r - 256) >> 1;
    const _Float16* Ap; const _Float16* Wp; const float* bs;
    int nk32, wk32;
    if (p1) {
      if (!odd) { Ap = AOv[(t+1)&1]; Wp = W1; bs = bs1; nk32 = 16; wk32 = 16; }
      else      { Ap = AOv[t&1];     Wp = W2; bs = bs2; nk32 = 32; wk32 = 32; }
    } else {
      if (!odd) { Ap = AFv[(s+1)&1]; Wp = W2; bs = bs2; nk32 = 32; wk32 = 32; }
      else      { Ap = AOv[s&1];     Wp = W2; bs = bs2; nk32 = 32; wk32 = 32; }
    }

    v4f acc[4][8];
    #pragma unroll
    for (int mt = 0; mt < 4; mt++)
      #pragma unroll
      for (int tt = 0; tt < 8; tt++) acc[mt][tt] = (v4f){0.f,0.f,0.f,0.f};

    const int itN = nk32 >> 2;
    const int it0 = wave * itN;
    const _Float16* pa[4];
    #pragma unroll
    for (int mt = 0; mt < 4; mt++)
      pa[mt] = Ap + (size_t)((bt*4+mt)*32)*512 + lane*8;
    const _Float16* pb[8];
    #pragma unroll
    for (int tt = 0; tt < 8; tt++) {
      int ntg = (tt>>1)*32 + ht*2 + (tt&1);
      pb[tt] = Wp + (size_t)ntg * wk32 * 512 + lane*8;
    }

    #pragma unroll 2
    for (int kk = it0; kk < it0 + itN; kk++) {
      v8h a[4], b[8];
      #pragma unroll
      for (int mt = 0; mt < 4; mt++)
        a[mt] = ld_frag_dev(pa[mt] + (size_t)kk*512);
      #pragma unroll
      for (int tt = 0; tt < 8; tt++)
        b[tt] = *(const v8h*)(pb[tt] + (size_t)kk*512);
      #pragma unroll
      for (int mt = 0; mt < 4; mt++)
        #pragma unroll
        for (int tt = 0; tt < 8; tt++)
          acc[mt][tt] = __builtin_amdgcn_mfma_f32_16x16x32_f16(a[mt], b[tt], acc[mt][tt], 0, 0, 0);
    }

    // ---- stage 1: waves 2,3 dump acc (b128, acc-frag layout) ----
    if (wave >= 2) {
      float* rg = lred + (wave - 2)*8192;
      #pragma unroll
      for (int mt = 0; mt < 4; mt++)
        #pragma unroll
        for (int tt = 0; tt < 8; tt++)
          *(v4f*)&rg[((mt*8 + tt)*64 + lane)*4] = acc[mt][tt];
    }
    __syncthreads();
    // ---- pair-add: wave0 += wave2's dump, wave1 += wave3's ----
    if (wave < 2) {
      const float* rg = lred + wave*8192;
      #pragma unroll
      for (int mt = 0; mt < 4; mt++)
        #pragma unroll
        for (int tt = 0; tt < 8; tt++)
          acc[mt][tt] += *(const v4f*)&rg[((mt*8 + tt)*64 + lane)*4];
    }
    __syncthreads();
    // ---- stage 2: waves 0,1 scatter combined halves into gate-major gred ----
    if (wave < 2) {
      float* gred = lred + wave*8192;   // rows of 128 floats, 64 rows
      #pragma unroll
      for (int mt = 0; mt < 4; mt++)
        #pragma unroll
        for (int tt = 0; tt < 8; tt++) {
          int row = mt*16 + quad*4;
          int col = tt*16 + lc;
          #pragma unroll
          for (int rr = 0; rr < 4; rr++) gred[(row + rr)*128 + col] = acc[mt][tt][rr];
        }
    }
    __syncthreads();

    // ---- fp32 LSTM epilogue: thread owns (b_loc, jj = oct*8 .. oct*8+7) ----
    float g[4][8];
    #pragma unroll
    for (int g4 = 0; g4 < 4; g4++) {
      #pragma unroll
      for (int j = 0; j < 8; j++) {
        int col = g4*32 + oct*8 + j;
        g[g4][j] = lred[b_loc*128 + col] + lred[8192 + b_loc*128 + col]
                 + bs[g4*512 + ht*32 + oct*8 + j];
      }
    }
    const int b = bt*64 + b_loc;
    if (!odd && p1) {                      // + x @ Wih1^T (K=4, exact fp32)
      const v4f xv = *(const v4f*)(x + ((size_t)t*1024 + b)*4);
      #pragma unroll
      for (int g4 = 0; g4 < 4; g4++)
        #pragma unroll
        for (int j = 0; j < 8; j++) {
          int hh = ht*32 + oct*8 + j;
          const v4f w = *(const v4f*)(Wih1 + (size_t)(g4*512 + hh)*4);
          g[g4][j] += xv[0]*w[0] + xv[1]*w[1] + xv[2]*w[2] + xv[3]*w[3];
        }
    }

    float hf[8];
    union { _Float16 h8[8]; unsigned long long u[2]; } hv;
    #pragma unroll
    for (int j = 0; j < 8; j++) {
      float ig = sigmoidf_(g[0][j]), fg = sigmoidf_(g[1][j]);
      float gg = tanhf_(g[2][j]),    og = sigmoidf_(g[3][j]);
      float c = odd ? c2[j] : c1[j];
      c = fg*c + ig*gg;
      if (odd) c2[j] = c; else c1[j] = c;
      hf[j] = og * tanhf_(c);
      hv.h8[j] = (_Float16)hf[j];
    }

    // ---- h stores: two 8B agent-relaxed atomics per 16B destination ----
    auto st16 = [&](_Float16* basep, int chunk) {
      unsigned long long* p = (unsigned long long*)(basep + (size_t)chunk*512 + lane_p*8);
      __hip_atomic_store(p,     hv.u[0], __ATOMIC_RELAXED, __HIP_MEMORY_SCOPE_AGENT);
      __hip_atomic_store(p + 1, hv.u[1], __ATOMIC_RELAXED, __HIP_MEMORY_SCOPE_AGENT);
    };
    const int cb = mtile_e*32;
    if (p1) {
      if (!odd) {                       // h1(t) -> AO[t&1].ht ; AF[t&1].16+ht
        st16(AOv[t&1], cb + ht);
        st16(AFv[t&1], cb + 16 + ht);
      } else {                          // h2(t) -> AO[(t+1)&1].16+ht ; tmp -> AF[0/1].ht
        st16(AOv[(t+1)&1], cb + 16 + ht);
        st16(AFv[0], cb + ht);
        st16(AFv[1], cb + ht);
      }
    } else {
      if (!odd) {                       // h1f(s) -> AF[s&1].16+ht ; AO[s&1].ht
        st16(AFv[s&1], cb + 16 + ht);
        st16(AOv[s&1], cb + ht);
      } else {                          // h2f(s) -> AO[(s+1)&1].16+ht
        st16(AOv[(s+1)&1], cb + 16 + ht);
      }
    }

    if (odd && !p1) {                   // out = h2f @ Wl^T + bl (partial over this ht's 32 cols)
      __syncthreads();                  // all lred reads done -> safe to alias stash
      float* stash = lred;              // [b_loc][33] fp32 h2
      #pragma unroll
      for (int j = 0; j < 8; j++) stash[b_loc*33 + oct*8 + j] = hf[j];
      __syncthreads();
      int bb = tid >> 2, o = tid & 3;
      float sacc = (ht == 0) ? blv[o] : 0.f;
      const float* wl = Wl + (size_t)o*512 + ht*32;
      #pragma unroll
      for (int jj = 0; jj < 32; jj++) sacc += stash[bb*33 + jj] * wl[jj];
      atomicAdd(&out[(((size_t)s*1024) + bt*64 + bb)*4 + o], sacc);
    }

    // ---- per-bt-group barrier: agent-relaxed add + relaxed poll ----
    __syncthreads();
    if (tid == 0) {
      int* ctr = bar + bt*32;           // 128B-spaced counters
      __hip_atomic_fetch_add(ctr, 1, __ATOMIC_RELAXED, __HIP_MEMORY_SCOPE_AGENT);
      const int target = 16*(r+1);
      while (__hip_atomic_load(ctr, __ATOMIC_RELAXED, __HIP_MEMORY_SCOPE_AGENT) < target)
        __builtin_amdgcn_s_sleep(1);
    }
    __syncthreads();
  }
}

extern "C" void kernel_launch(void* const* d_in, const int* in_sizes, int n_in,
                              void* d_out, int out_size, void* d_ws, size_t ws_size,
                              hipStream_t stream) {
  const float* x    = (const float*)d_in[0];
  const float* Wih1 = (const float*)d_in[1];
  const float* Whh1 = (const float*)d_in[2];
  const float* bih1 = (const float*)d_in[3];
  const float* bhh1 = (const float*)d_in[4];
  const float* Wih2 = (const float*)d_in[5];
  const float* Whh2 = (const float*)d_in[6];
  const float* bih2 = (const float*)d_in[7];
  const float* bhh2 = (const float*)d_in[8];
  const float* Wl   = (const float*)d_in[9];
  const float* bl   = (const float*)d_in[10];

  char* ws = (char*)d_ws;
  int*      bar = (int*)(ws + OFF_BAR);
  _Float16* AO0 = (_Float16*)(ws + OFF_AO0);
  _Float16* AO1 = (_Float16*)(ws + OFF_AO1);
  _Float16* AF0 = (_Float16*)(ws + OFF_AF0);
  _Float16* AF1 = (_Float16*)(ws + OFF_AF1);
  _Float16* W1p = (_Float16*)(ws + OFF_W1);
  _Float16* W2p = (_Float16*)(ws + OFF_W2);
  float*    bs1 = (float*)(ws + OFF_B1);
  float*    bs2 = (float*)(ws + OFF_B2);

  // zero barrier + state buffers (h,c start at 0); zero out (atomic accumulation)
  hipMemsetAsync(ws, 0, (size_t)OFF_W1, stream);
  hipMemsetAsync(d_out, 0, (size_t)out_size * sizeof(float), stream);

  lstm_prep<<<2048, 256, 0, stream>>>(Whh1, Wih2, Whh2, bih1, bhh1, bih2, bhh2,
                                      W1p, W2p, bs1, bs2);
  lstm_main<<<256, 256, 0, stream>>>(x, Wih1, Wl, bl, AO0, AO1, AF0, AF1,
                                     W1p, W2p, bs1, bs2, bar, (float*)d_out);
}